// Round 9
// baseline (392.400 us; speedup 1.0000x reference)
//
#include <hip/hip_runtime.h>

#define B_ 4
#define C_ 64
#define H_ 256
#define W_ 256
#define HW_ (H_*W_)
#define MID_ 12
#define NPB_ 256   // gap partial slots per image (= one per row-block)

__device__ __forceinline__ float wave_reduce64(float v) {
#pragma unroll
    for (int off = 32; off; off >>= 1) v += __shfl_xor(v, off, 64);
    return v;
}

// FilterNorm over 9 taps, vectorized over 4 px; writes to sp (stride HW_)
__device__ __forceinline__ void fnorm4_store(const float4* t9,
    const float* __restrict__ sstd, float* sp) {
    float4 mean = make_float4(0, 0, 0, 0);
#pragma unroll
    for (int t = 0; t < 9; ++t) {
        mean.x += t9[t].x; mean.y += t9[t].y; mean.z += t9[t].z; mean.w += t9[t].w;
    }
    mean.x *= (1.f/9.f); mean.y *= (1.f/9.f); mean.z *= (1.f/9.f); mean.w *= (1.f/9.f);
    float4 var = make_float4(0, 0, 0, 0);
#pragma unroll
    for (int t = 0; t < 9; ++t) {
        float dx = t9[t].x - mean.x, dy = t9[t].y - mean.y;
        float dz = t9[t].z - mean.z, dw = t9[t].w - mean.w;
        var.x = fmaf(dx, dx, var.x); var.y = fmaf(dy, dy, var.y);
        var.z = fmaf(dz, dz, var.z); var.w = fmaf(dw, dw, var.w);
    }
    float ix = 1.f / (sqrtf(var.x * (1.f/8.f)) + 1e-10f);
    float iy = 1.f / (sqrtf(var.y * (1.f/8.f)) + 1e-10f);
    float iz = 1.f / (sqrtf(var.z * (1.f/8.f)) + 1e-10f);
    float iw = 1.f / (sqrtf(var.w * (1.f/8.f)) + 1e-10f);
#pragma unroll
    for (int t = 0; t < 9; ++t) {
        float sd = sstd[t];
        *(float4*)(sp + (size_t)t * HW_) = make_float4(
            (t9[t].x - mean.x) * ix * sd, (t9[t].y - mean.y) * iy * sd,
            (t9[t].z - mean.z) * iz * sd, (t9[t].w - mean.w) * iw * sd);
    }
}

// ---------------- prep: read x once -> s1 + gap1 partials ----------------
// block = 1 row, 4 waves x 16 channels; lane = 4 px (float4). grid (H, B).
__global__ __launch_bounds__(256, 4) void prep_kernel(const float* __restrict__ x,
    const float* __restrict__ sw, const float* __restrict__ sb,
    const float* __restrict__ sstd, float* __restrict__ sarr, float* __restrict__ gp) {
    const int lane = threadIdx.x & 63, wv = threadIdx.x >> 6;
    const int row = blockIdx.x;
    const int b = blockIdx.y;
    const int c0 = wv * 16;
    const int pix = row * W_ + lane * 4;
    __shared__ float4 stl[3][9][64];

    float4 st[9];
#pragma unroll
    for (int t = 0; t < 9; ++t) st[t] = make_float4(0, 0, 0, 0);

    const float* xb = x + (size_t)b * C_ * HW_ + pix;
    float4 vA[4], vB[4];
#pragma unroll
    for (int i = 0; i < 4; ++i) vA[i] = *(const float4*)(xb + (size_t)(c0 + i) * HW_);

#define PREP_COMP(BUF, CC) do {                                               \
        _Pragma("unroll")                                                     \
        for (int i_ = 0; i_ < 4; ++i_) {                                      \
            const int c_ = (CC) + i_;                                         \
            float4 v_ = BUF[i_];                                              \
            _Pragma("unroll")                                                 \
            for (int t_ = 0; t_ < 9; ++t_) {                                  \
                const float wt_ = sw[t_ * C_ + c_];                           \
                st[t_].x = fmaf(v_.x, wt_, st[t_].x);                         \
                st[t_].y = fmaf(v_.y, wt_, st[t_].y);                         \
                st[t_].z = fmaf(v_.z, wt_, st[t_].z);                         \
                st[t_].w = fmaf(v_.w, wt_, st[t_].w);                         \
            }                                                                 \
            float g_ = wave_reduce64(((v_.x + v_.y) + (v_.z + v_.w)));        \
            if (lane == 0) gp[((size_t)b * C_ + c_) * NPB_ + blockIdx.x] = g_; \
        }                                                                     \
    } while (0)

    for (int k = 0; k < 16; k += 8) {
#pragma unroll
        for (int i = 0; i < 4; ++i) vB[i] = *(const float4*)(xb + (size_t)(c0 + k + 4 + i) * HW_);
        PREP_COMP(vA, c0 + k);
        if (k + 8 < 16) {
#pragma unroll
            for (int i = 0; i < 4; ++i) vA[i] = *(const float4*)(xb + (size_t)(c0 + k + 8 + i) * HW_);
        }
        PREP_COMP(vB, c0 + k + 4);
    }
#undef PREP_COMP

    if (wv) {
#pragma unroll
        for (int t = 0; t < 9; ++t) stl[wv - 1][t][lane] = st[t];
    }
    __syncthreads();
    if (wv == 0) {
#pragma unroll
        for (int t = 0; t < 9; ++t) {
            float bb = sb[t];
#pragma unroll
            for (int j = 0; j < 3; ++j) {
                float4 o = stl[j][t][lane];
                st[t].x += o.x; st[t].y += o.y; st[t].z += o.z; st[t].w += o.w;
            }
            st[t].x += bb; st[t].y += bb; st[t].z += bb; st[t].w += bb;
        }
        fnorm4_store(st, sstd, sarr + ((size_t)b * 9) * HW_ + pix);
    }
}

// ------ cfk: reduce gap partials + SE MLP + FilterNorm -> cf (B,C,12 padded) ------
__global__ __launch_bounds__(256) void cfk(const float* __restrict__ gp,
    const float* __restrict__ cw1, const float* __restrict__ cb1,
    const float* __restrict__ cw2, const float* __restrict__ cb2,
    const float* __restrict__ cstd, float* __restrict__ cf) {
    const int tid = threadIdx.x;
    const int b = tid >> 6, c = tid & 63;
    __shared__ float gsm[B_][C_];
    __shared__ float hsm[B_][MID_];
    {
        const float4* p4 = (const float4*)(gp + ((size_t)b * C_ + c) * NPB_);
        float s = 0.f;
#pragma unroll 8
        for (int i = 0; i < NPB_ / 4; ++i) { float4 v = p4[i]; s += (v.x + v.y) + (v.z + v.w); }
        gsm[b][c] = s * (1.f / HW_);
    }
    __syncthreads();
    if (tid < B_ * MID_) {
        int b2 = tid / MID_, m = tid % MID_;
        float a = cb1[m];
        for (int cc = 0; cc < C_; ++cc) a = fmaf(gsm[b2][cc], cw1[m * C_ + cc], a);
        hsm[b2][m] = fmaxf(a, 0.f);
    }
    __syncthreads();
    float v[9];
    float mean = 0.f;
#pragma unroll
    for (int t = 0; t < 9; ++t) {
        int o = c * 9 + t;
        float a = cb2[o];
#pragma unroll
        for (int m = 0; m < MID_; ++m) a = fmaf(hsm[b][m], cw2[o * MID_ + m], a);
        v[t] = a;
        mean += a;
    }
    mean *= (1.f / 9.f);
    float var = 0.f;
#pragma unroll
    for (int t = 0; t < 9; ++t) { float d = v[t] - mean; var += d * d; }
    float inv = 1.f / (sqrtf(var * (1.f / 8.f)) + 1e-10f);
    float* o12 = cf + ((size_t)b * C_ + c) * 12;
#pragma unroll
    for (int t = 0; t < 9; ++t) o12[t] = (v[t] - mean) * inv * cstd[c * 9 + t];
    o12[9] = 0.f; o12[10] = 0.f; o12[11] = 0.f;
}

// ---------- apply: full-row block, 4 waves x 16 channels, register halo ----------
// grid (H, B); XCD-bijective row swizzle. PASS1 fuses relu + s_next + gap.
template<bool PASS1, int MINW>
__global__ __launch_bounds__(256, MINW) void apply_kernel(const float* __restrict__ in,
    const float* __restrict__ sarr, const float* __restrict__ cf,
    const float* __restrict__ swn, const float* __restrict__ sbn,
    const float* __restrict__ sstdn, const float* __restrict__ resid,
    float* __restrict__ out, float* __restrict__ snext, float* __restrict__ gpn) {
    const int lane = threadIdx.x & 63, wv = threadIdx.x >> 6;
    const int f = blockIdx.x;
    const int row = ((f & 7) << 5) | (f >> 3);   // XCD k -> rows [32k, 32k+32)
    const int b = blockIdx.y;
    const int c0 = wv * 16;
    const int pix = row * W_ + lane * 4;

    const bool rup = row > 0, rdn = row < H_ - 1;
    const int offUp = rup ? -W_ : 0;
    const int offDn = rdn ? W_ : 0;
    const float fup = rup ? 1.f : 0.f;
    const float fdn = rdn ? 1.f : 0.f;

    // per-pixel s taps; fold ALL edge masks here
    float4 s0t[9];
    {
        const float* sp = sarr + ((size_t)b * 9) * HW_ + pix;
#pragma unroll
        for (int t = 0; t < 9; ++t) s0t[t] = *(const float4*)(sp + (size_t)t * HW_);
#pragma unroll
        for (int t = 0; t < 3; ++t) {
            s0t[t].x *= fup; s0t[t].y *= fup; s0t[t].z *= fup; s0t[t].w *= fup;
            s0t[t + 6].x *= fdn; s0t[t + 6].y *= fdn; s0t[t + 6].z *= fdn; s0t[t + 6].w *= fdn;
        }
        if (lane == 0)  { s0t[0].x = 0.f; s0t[3].x = 0.f; s0t[6].x = 0.f; }
        if (lane == 63) { s0t[2].w = 0.f; s0t[5].w = 0.f; s0t[8].w = 0.f; }
    }

    float4 nt[9];
    if (PASS1) {
#pragma unroll
        for (int t = 0; t < 9; ++t) nt[t] = make_float4(0, 0, 0, 0);
    }

    const float* inb = in + (size_t)b * C_ * HW_ + pix;
    const float* cfb = cf + ((size_t)b * C_) * 12;
    const float* rb  = PASS1 ? nullptr : (resid + (size_t)b * C_ * HW_ + pix);
    float* outp = out + (size_t)b * C_ * HW_ + pix;

    float4 bufA[2][3], bufB[2][3], rA[2], rB[2];

#define LOADB(BUF, RV, CH0) do {                                              \
        _Pragma("unroll")                                                     \
        for (int i_ = 0; i_ < 2; ++i_) {                                      \
            const float* p_ = inb + (size_t)((CH0) + i_) * HW_;               \
            BUF[i_][0] = *(const float4*)(p_ + offUp);                        \
            BUF[i_][1] = *(const float4*)(p_);                                \
            BUF[i_][2] = *(const float4*)(p_ + offDn);                        \
            if (!PASS1) RV[i_] = *(const float4*)(rb + (size_t)((CH0) + i_) * HW_); \
        }                                                                     \
    } while (0)

#define COMPB(BUF, RV, CH0) do {                                              \
        _Pragma("unroll")                                                     \
        for (int i_ = 0; i_ < 2; ++i_) {                                      \
            const int ch_ = (CH0) + i_;                                       \
            const float* cfc_ = cfb + (size_t)ch_ * 12;                       \
            float4 acc_ = make_float4(0.f, 0.f, 0.f, 0.f);                    \
            _Pragma("unroll")                                                 \
            for (int dr_ = 0; dr_ < 3; ++dr_) {                               \
                float4 v_ = BUF[i_][dr_];                                     \
                float w0_ = __shfl_up(v_.w, 1, 64);                           \
                float w5_ = __shfl_down(v_.x, 1, 64);                         \
                const float w_[6] = {w0_, v_.x, v_.y, v_.z, v_.w, w5_};       \
                _Pragma("unroll")                                             \
                for (int dc_ = 0; dc_ < 3; ++dc_) {                           \
                    const int t_ = dr_ * 3 + dc_;                             \
                    const float cft_ = cfc_[t_];                              \
                    acc_.x = fmaf(w_[dc_ + 0] * s0t[t_].x, cft_, acc_.x);     \
                    acc_.y = fmaf(w_[dc_ + 1] * s0t[t_].y, cft_, acc_.y);     \
                    acc_.z = fmaf(w_[dc_ + 2] * s0t[t_].z, cft_, acc_.z);     \
                    acc_.w = fmaf(w_[dc_ + 3] * s0t[t_].w, cft_, acc_.w);     \
                }                                                             \
            }                                                                 \
            float4 o_;                                                        \
            if (PASS1) {                                                      \
                o_.x = fmaxf(acc_.x, 0.f); o_.y = fmaxf(acc_.y, 0.f);         \
                o_.z = fmaxf(acc_.z, 0.f); o_.w = fmaxf(acc_.w, 0.f);         \
                _Pragma("unroll")                                             \
                for (int t_ = 0; t_ < 9; ++t_) {                              \
                    const float wt_ = swn[t_ * C_ + ch_];                     \
                    nt[t_].x = fmaf(o_.x, wt_, nt[t_].x);                     \
                    nt[t_].y = fmaf(o_.y, wt_, nt[t_].y);                     \
                    nt[t_].z = fmaf(o_.z, wt_, nt[t_].z);                     \
                    nt[t_].w = fmaf(o_.w, wt_, nt[t_].w);                     \
                }                                                             \
                float g_ = wave_reduce64(((o_.x + o_.y) + (o_.z + o_.w)));    \
                if (lane == 0) gpn[((size_t)b * C_ + ch_) * NPB_ + f] = g_;   \
            } else {                                                          \
                o_.x = acc_.x + RV[i_].x; o_.y = acc_.y + RV[i_].y;           \
                o_.z = acc_.z + RV[i_].z; o_.w = acc_.w + RV[i_].w;           \
            }                                                                 \
            *(float4*)(outp + (size_t)ch_ * HW_) = o_;                        \
        }                                                                     \
    } while (0)

    LOADB(bufA, rA, c0);
#pragma unroll
    for (int k = 0; k < 16; k += 4) {
        LOADB(bufB, rB, c0 + k + 2);
        COMPB(bufA, rA, c0 + k);
        if (k + 4 < 16) LOADB(bufA, rA, c0 + k + 4);
        COMPB(bufB, rB, c0 + k + 2);
    }
#undef LOADB
#undef COMPB

    if constexpr (PASS1) {
        __shared__ float4 ntl[3][9][64];
        if (wv) {
#pragma unroll
            for (int t = 0; t < 9; ++t) ntl[wv - 1][t][lane] = nt[t];
        }
        __syncthreads();
        if (wv == 0) {
#pragma unroll
            for (int t = 0; t < 9; ++t) {
                float bb = sbn[t];
#pragma unroll
                for (int j = 0; j < 3; ++j) {
                    float4 o = ntl[j][t][lane];
                    nt[t].x += o.x; nt[t].y += o.y; nt[t].z += o.z; nt[t].w += o.w;
                }
                nt[t].x += bb; nt[t].y += bb; nt[t].z += bb; nt[t].w += bb;
            }
            fnorm4_store(nt, sstdn, snext + ((size_t)b * 9) * HW_ + pix);
        }
    }
}

extern "C" void kernel_launch(void* const* d_in, const int* in_sizes, int n_in,
                              void* d_out, int out_size, void* d_ws, size_t ws_size,
                              hipStream_t stream) {
    const float* x     = (const float*)d_in[0];
    const float* sw1   = (const float*)d_in[1];
    const float* sb1   = (const float*)d_in[2];
    const float* sstd1 = (const float*)d_in[3];
    const float* cw1_1 = (const float*)d_in[4];
    const float* cb1_1 = (const float*)d_in[5];
    const float* cw2_1 = (const float*)d_in[6];
    const float* cb2_1 = (const float*)d_in[7];
    const float* cstd1 = (const float*)d_in[8];
    const float* sw2   = (const float*)d_in[9];
    const float* sb2   = (const float*)d_in[10];
    const float* sstd2 = (const float*)d_in[11];
    const float* cw1_2 = (const float*)d_in[12];
    const float* cb1_2 = (const float*)d_in[13];
    const float* cw2_2 = (const float*)d_in[14];
    const float* cb2_2 = (const float*)d_in[15];
    const float* cstd2 = (const float*)d_in[16];
    float* outp = (float*)d_out;

    const size_t n_out1 = (size_t)B_ * C_ * HW_;     // 16,777,216
    const size_t n_s    = (size_t)B_ * 9 * HW_;      // 2,359,296
    const size_t n_cf   = (size_t)B_ * C_ * 12;      // 3,072 (padded)
    const size_t n_gp   = (size_t)B_ * C_ * NPB_;    // 65,536
    const size_t need = (n_out1 + 2 * n_s + 2 * n_cf + 2 * n_gp) * sizeof(float);
    if (ws_size < need) return;

    float* out1 = (float*)d_ws;
    float* s1   = out1 + n_out1;
    float* s2   = s1 + n_s;
    float* cf1  = s2 + n_s;
    float* cf2  = cf1 + n_cf;
    float* gp1  = cf2 + n_cf;
    float* gp2  = gp1 + n_gp;

    dim3 g(H_, B_);   // 1024 blocks, block = 1 row x 64 channels (4 waves x 16)

    prep_kernel<<<g, 256, 0, stream>>>(x, sw1, sb1, sstd1, s1, gp1);
    cfk<<<1, 256, 0, stream>>>(gp1, cw1_1, cb1_1, cw2_1, cb2_1, cstd1, cf1);
    apply_kernel<true, 3><<<g, 256, 0, stream>>>(x, s1, cf1, sw2, sb2, sstd2,
                                                 nullptr, out1, s2, gp2);
    cfk<<<1, 256, 0, stream>>>(gp2, cw1_2, cb1_2, cw2_2, cb2_2, cstd2, cf2);
    apply_kernel<false, 4><<<g, 256, 0, stream>>>(out1, s2, cf2, nullptr, nullptr,
                                                  nullptr, x, outp, nullptr, nullptr);
}

// Round 10
// 185.196 us; speedup vs baseline: 2.1188x; 2.1188x over previous
//
#include <hip/hip_runtime.h>

#define B_ 4
#define C_ 64
#define H_ 256
#define W_ 256
#define HW_ (H_*W_)
#define MID_ 12
#define NPB_ 256   // gap partial slots per image (= one per row)

__device__ __forceinline__ float wave_reduce64(float v) {
#pragma unroll
    for (int off = 32; off; off >>= 1) v += __shfl_xor(v, off, 64);
    return v;
}

// FilterNorm over 9 taps, vectorized over 4 px; writes to sp (stride HW_)
__device__ __forceinline__ void fnorm4_store(const float4* t9,
    const float* __restrict__ sstd, float* sp) {
    float4 mean = make_float4(0, 0, 0, 0);
#pragma unroll
    for (int t = 0; t < 9; ++t) {
        mean.x += t9[t].x; mean.y += t9[t].y; mean.z += t9[t].z; mean.w += t9[t].w;
    }
    mean.x *= (1.f/9.f); mean.y *= (1.f/9.f); mean.z *= (1.f/9.f); mean.w *= (1.f/9.f);
    float4 var = make_float4(0, 0, 0, 0);
#pragma unroll
    for (int t = 0; t < 9; ++t) {
        float dx = t9[t].x - mean.x, dy = t9[t].y - mean.y;
        float dz = t9[t].z - mean.z, dw = t9[t].w - mean.w;
        var.x = fmaf(dx, dx, var.x); var.y = fmaf(dy, dy, var.y);
        var.z = fmaf(dz, dz, var.z); var.w = fmaf(dw, dw, var.w);
    }
    float ix = 1.f / (sqrtf(var.x * (1.f/8.f)) + 1e-10f);
    float iy = 1.f / (sqrtf(var.y * (1.f/8.f)) + 1e-10f);
    float iz = 1.f / (sqrtf(var.z * (1.f/8.f)) + 1e-10f);
    float iw = 1.f / (sqrtf(var.w * (1.f/8.f)) + 1e-10f);
#pragma unroll
    for (int t = 0; t < 9; ++t) {
        float sd = sstd[t];
        *(float4*)(sp + (size_t)t * HW_) = make_float4(
            (t9[t].x - mean.x) * ix * sd, (t9[t].y - mean.y) * iy * sd,
            (t9[t].z - mean.z) * iz * sd, (t9[t].w - mean.w) * iw * sd);
    }
}

// ---------------- prep: read x once -> s1 + gap1 partials ----------------
// block = 1 row, 4 waves x 16 channels; lane = 4 px (float4). grid (H, B).
__global__ __launch_bounds__(256) void prep_kernel(const float* __restrict__ x,
    const float* __restrict__ sw, const float* __restrict__ sb,
    const float* __restrict__ sstd, float* __restrict__ sarr, float* __restrict__ gp) {
    const int lane = threadIdx.x & 63, wv = threadIdx.x >> 6;
    const int row = blockIdx.x;
    const int b = blockIdx.y;
    const int c0 = wv * 16;
    const int pix = row * W_ + lane * 4;
    __shared__ float4 stl[3][9][64];

    float4 st[9];
#pragma unroll
    for (int t = 0; t < 9; ++t) st[t] = make_float4(0, 0, 0, 0);

    const float* xb = x + (size_t)b * C_ * HW_ + pix;
    float4 vA[4], vB[4];
#pragma unroll
    for (int i = 0; i < 4; ++i) vA[i] = *(const float4*)(xb + (size_t)(c0 + i) * HW_);

#define PREP_COMP(BUF, CC) do {                                               \
        _Pragma("unroll")                                                     \
        for (int i_ = 0; i_ < 4; ++i_) {                                      \
            const int c_ = (CC) + i_;                                         \
            float4 v_ = BUF[i_];                                              \
            _Pragma("unroll")                                                 \
            for (int t_ = 0; t_ < 9; ++t_) {                                  \
                const float wt_ = sw[t_ * C_ + c_];                           \
                st[t_].x = fmaf(v_.x, wt_, st[t_].x);                         \
                st[t_].y = fmaf(v_.y, wt_, st[t_].y);                         \
                st[t_].z = fmaf(v_.z, wt_, st[t_].z);                         \
                st[t_].w = fmaf(v_.w, wt_, st[t_].w);                         \
            }                                                                 \
            float g_ = wave_reduce64(((v_.x + v_.y) + (v_.z + v_.w)));        \
            if (lane == 0) gp[((size_t)b * C_ + c_) * NPB_ + blockIdx.x] = g_; \
        }                                                                     \
    } while (0)

    for (int k = 0; k < 16; k += 8) {
#pragma unroll
        for (int i = 0; i < 4; ++i) vB[i] = *(const float4*)(xb + (size_t)(c0 + k + 4 + i) * HW_);
        PREP_COMP(vA, c0 + k);
        if (k + 8 < 16) {
#pragma unroll
            for (int i = 0; i < 4; ++i) vA[i] = *(const float4*)(xb + (size_t)(c0 + k + 8 + i) * HW_);
        }
        PREP_COMP(vB, c0 + k + 4);
    }
#undef PREP_COMP

    if (wv) {
#pragma unroll
        for (int t = 0; t < 9; ++t) stl[wv - 1][t][lane] = st[t];
    }
    __syncthreads();
    if (wv == 0) {
#pragma unroll
        for (int t = 0; t < 9; ++t) {
            float bb = sb[t];
#pragma unroll
            for (int j = 0; j < 3; ++j) {
                float4 o = stl[j][t][lane];
                st[t].x += o.x; st[t].y += o.y; st[t].z += o.z; st[t].w += o.w;
            }
            st[t].x += bb; st[t].y += bb; st[t].z += bb; st[t].w += bb;
        }
        fnorm4_store(st, sstd, sarr + ((size_t)b * 9) * HW_ + pix);
    }
}

// ------ cfk: reduce gap partials + SE MLP + FilterNorm -> cf (B,C,12 padded) ------
__global__ __launch_bounds__(256) void cfk(const float* __restrict__ gp,
    const float* __restrict__ cw1, const float* __restrict__ cb1,
    const float* __restrict__ cw2, const float* __restrict__ cb2,
    const float* __restrict__ cstd, float* __restrict__ cf) {
    const int tid = threadIdx.x;
    const int b = tid >> 6, c = tid & 63;
    __shared__ float gsm[B_][C_];
    __shared__ float hsm[B_][MID_];
    {
        const float4* p4 = (const float4*)(gp + ((size_t)b * C_ + c) * NPB_);
        float s = 0.f;
#pragma unroll 8
        for (int i = 0; i < NPB_ / 4; ++i) { float4 v = p4[i]; s += (v.x + v.y) + (v.z + v.w); }
        gsm[b][c] = s * (1.f / HW_);
    }
    __syncthreads();
    if (tid < B_ * MID_) {
        int b2 = tid / MID_, m = tid % MID_;
        float a = cb1[m];
        for (int cc = 0; cc < C_; ++cc) a = fmaf(gsm[b2][cc], cw1[m * C_ + cc], a);
        hsm[b2][m] = fmaxf(a, 0.f);
    }
    __syncthreads();
    float v[9];
    float mean = 0.f;
#pragma unroll
    for (int t = 0; t < 9; ++t) {
        int o = c * 9 + t;
        float a = cb2[o];
#pragma unroll
        for (int m = 0; m < MID_; ++m) a = fmaf(hsm[b][m], cw2[o * MID_ + m], a);
        v[t] = a;
        mean += a;
    }
    mean *= (1.f / 9.f);
    float var = 0.f;
#pragma unroll
    for (int t = 0; t < 9; ++t) { float d = v[t] - mean; var += d * d; }
    float inv = 1.f / (sqrtf(var * (1.f / 8.f)) + 1e-10f);
    float* o12 = cf + ((size_t)b * C_ + c) * 12;
#pragma unroll
    for (int t = 0; t < 9; ++t) o12[t] = (v[t] - mean) * inv * cstd[c * 9 + t];
    o12[9] = 0.f; o12[10] = 0.f; o12[11] = 0.f;
}

// ---------- apply: full-row block, channels split across waves ----------
// PASS1: grid (H, B), 16 ch/wave, fused relu + s_next + gap.
// PASS2: grid (H, B, 2), 8 ch/wave, + residual.
template<bool PASS1>
__global__ __launch_bounds__(256) void apply_kernel(const float* __restrict__ in,
    const float* __restrict__ sarr, const float* __restrict__ cf,
    const float* __restrict__ swn, const float* __restrict__ sbn,
    const float* __restrict__ sstdn, const float* __restrict__ resid,
    float* __restrict__ out, float* __restrict__ snext, float* __restrict__ gpn) {
    const int lane = threadIdx.x & 63, wv = threadIdx.x >> 6;
    const int row = blockIdx.x;
    const int b = blockIdx.y;
    constexpr int NCHW = PASS1 ? 16 : 8;
    const int c0 = PASS1 ? (wv * 16) : (blockIdx.z * 32 + wv * 8);
    const int pix = row * W_ + lane * 4;

    const bool rup = row > 0, rdn = row < H_ - 1;
    const int offUp = rup ? -W_ : 0;
    const int offDn = rdn ? W_ : 0;
    const float fup = rup ? 1.f : 0.f;
    const float fdn = rdn ? 1.f : 0.f;

    // per-pixel s taps; fold ALL edge masks here
    float4 s0t[9];
    {
        const float* sp = sarr + ((size_t)b * 9) * HW_ + pix;
#pragma unroll
        for (int t = 0; t < 9; ++t) s0t[t] = *(const float4*)(sp + (size_t)t * HW_);
#pragma unroll
        for (int t = 0; t < 3; ++t) {
            s0t[t].x *= fup; s0t[t].y *= fup; s0t[t].z *= fup; s0t[t].w *= fup;
            s0t[t + 6].x *= fdn; s0t[t + 6].y *= fdn; s0t[t + 6].z *= fdn; s0t[t + 6].w *= fdn;
        }
        if (lane == 0)  { s0t[0].x = 0.f; s0t[3].x = 0.f; s0t[6].x = 0.f; }
        if (lane == 63) { s0t[2].w = 0.f; s0t[5].w = 0.f; s0t[8].w = 0.f; }
    }

    float4 nt[9];
    if (PASS1) {
#pragma unroll
        for (int t = 0; t < 9; ++t) nt[t] = make_float4(0, 0, 0, 0);
    }

    const float* inb = in + (size_t)b * C_ * HW_ + pix;
    const float* cfb = cf + ((size_t)b * C_) * 12;
    const float* rb  = PASS1 ? nullptr : (resid + (size_t)b * C_ * HW_ + pix);
    float* outp = out + (size_t)b * C_ * HW_ + pix;

    float4 bufA[2][3], bufB[2][3], rA[2], rB[2];

#define LOADB(BUF, RV, CH0) do {                                              \
        _Pragma("unroll")                                                     \
        for (int i_ = 0; i_ < 2; ++i_) {                                      \
            const float* p_ = inb + (size_t)((CH0) + i_) * HW_;               \
            BUF[i_][0] = *(const float4*)(p_ + offUp);                        \
            BUF[i_][1] = *(const float4*)(p_);                                \
            BUF[i_][2] = *(const float4*)(p_ + offDn);                        \
            if (!PASS1) RV[i_] = *(const float4*)(rb + (size_t)((CH0) + i_) * HW_); \
        }                                                                     \
    } while (0)

#define COMPB(BUF, RV, CH0) do {                                              \
        _Pragma("unroll")                                                     \
        for (int i_ = 0; i_ < 2; ++i_) {                                      \
            const int ch_ = (CH0) + i_;                                       \
            const float* cfc_ = cfb + (size_t)ch_ * 12;                       \
            float4 acc_ = make_float4(0.f, 0.f, 0.f, 0.f);                    \
            _Pragma("unroll")                                                 \
            for (int dr_ = 0; dr_ < 3; ++dr_) {                               \
                float4 v_ = BUF[i_][dr_];                                     \
                float w0_ = __shfl_up(v_.w, 1, 64);                           \
                float w5_ = __shfl_down(v_.x, 1, 64);                         \
                const float w_[6] = {w0_, v_.x, v_.y, v_.z, v_.w, w5_};       \
                _Pragma("unroll")                                             \
                for (int dc_ = 0; dc_ < 3; ++dc_) {                           \
                    const int t_ = dr_ * 3 + dc_;                             \
                    const float cft_ = cfc_[t_];                              \
                    acc_.x = fmaf(w_[dc_ + 0] * s0t[t_].x, cft_, acc_.x);     \
                    acc_.y = fmaf(w_[dc_ + 1] * s0t[t_].y, cft_, acc_.y);     \
                    acc_.z = fmaf(w_[dc_ + 2] * s0t[t_].z, cft_, acc_.z);     \
                    acc_.w = fmaf(w_[dc_ + 3] * s0t[t_].w, cft_, acc_.w);     \
                }                                                             \
            }                                                                 \
            float4 o_;                                                        \
            if (PASS1) {                                                      \
                o_.x = fmaxf(acc_.x, 0.f); o_.y = fmaxf(acc_.y, 0.f);         \
                o_.z = fmaxf(acc_.z, 0.f); o_.w = fmaxf(acc_.w, 0.f);         \
                _Pragma("unroll")                                             \
                for (int t_ = 0; t_ < 9; ++t_) {                              \
                    const float wt_ = swn[t_ * C_ + ch_];                     \
                    nt[t_].x = fmaf(o_.x, wt_, nt[t_].x);                     \
                    nt[t_].y = fmaf(o_.y, wt_, nt[t_].y);                     \
                    nt[t_].z = fmaf(o_.z, wt_, nt[t_].z);                     \
                    nt[t_].w = fmaf(o_.w, wt_, nt[t_].w);                     \
                }                                                             \
                float g_ = wave_reduce64(((o_.x + o_.y) + (o_.z + o_.w)));    \
                if (lane == 0) gpn[((size_t)b * C_ + ch_) * NPB_ + blockIdx.x] = g_; \
            } else {                                                          \
                o_.x = acc_.x + RV[i_].x; o_.y = acc_.y + RV[i_].y;           \
                o_.z = acc_.z + RV[i_].z; o_.w = acc_.w + RV[i_].w;           \
            }                                                                 \
            *(float4*)(outp + (size_t)ch_ * HW_) = o_;                        \
        }                                                                     \
    } while (0)

    LOADB(bufA, rA, c0);
#pragma unroll
    for (int k = 0; k < NCHW; k += 4) {
        LOADB(bufB, rB, c0 + k + 2);
        COMPB(bufA, rA, c0 + k);
        if (k + 4 < NCHW) LOADB(bufA, rA, c0 + k + 4);
        COMPB(bufB, rB, c0 + k + 2);
    }
#undef LOADB
#undef COMPB

    if constexpr (PASS1) {
        __shared__ float4 ntl[3][9][64];
        if (wv) {
#pragma unroll
            for (int t = 0; t < 9; ++t) ntl[wv - 1][t][lane] = nt[t];
        }
        __syncthreads();
        if (wv == 0) {
#pragma unroll
            for (int t = 0; t < 9; ++t) {
                float bb = sbn[t];
#pragma unroll
                for (int j = 0; j < 3; ++j) {
                    float4 o = ntl[j][t][lane];
                    nt[t].x += o.x; nt[t].y += o.y; nt[t].z += o.z; nt[t].w += o.w;
                }
                nt[t].x += bb; nt[t].y += bb; nt[t].z += bb; nt[t].w += bb;
            }
            fnorm4_store(nt, sstdn, snext + ((size_t)b * 9) * HW_ + pix);
        }
    }
}

extern "C" void kernel_launch(void* const* d_in, const int* in_sizes, int n_in,
                              void* d_out, int out_size, void* d_ws, size_t ws_size,
                              hipStream_t stream) {
    const float* x     = (const float*)d_in[0];
    const float* sw1   = (const float*)d_in[1];
    const float* sb1   = (const float*)d_in[2];
    const float* sstd1 = (const float*)d_in[3];
    const float* cw1_1 = (const float*)d_in[4];
    const float* cb1_1 = (const float*)d_in[5];
    const float* cw2_1 = (const float*)d_in[6];
    const float* cb2_1 = (const float*)d_in[7];
    const float* cstd1 = (const float*)d_in[8];
    const float* sw2   = (const float*)d_in[9];
    const float* sb2   = (const float*)d_in[10];
    const float* sstd2 = (const float*)d_in[11];
    const float* cw1_2 = (const float*)d_in[12];
    const float* cb1_2 = (const float*)d_in[13];
    const float* cw2_2 = (const float*)d_in[14];
    const float* cb2_2 = (const float*)d_in[15];
    const float* cstd2 = (const float*)d_in[16];
    float* outp = (float*)d_out;

    const size_t n_out1 = (size_t)B_ * C_ * HW_;     // 16,777,216
    const size_t n_s    = (size_t)B_ * 9 * HW_;      // 2,359,296
    const size_t n_cf   = (size_t)B_ * C_ * 12;      // 3,072 (padded)
    const size_t n_gp   = (size_t)B_ * C_ * NPB_;    // 65,536
    const size_t need = (n_out1 + 2 * n_s + 2 * n_cf + 2 * n_gp) * sizeof(float);
    if (ws_size < need) return;

    float* out1 = (float*)d_ws;
    float* s1   = out1 + n_out1;
    float* s2   = s1 + n_s;
    float* cf1  = s2 + n_s;
    float* cf2  = cf1 + n_cf;
    float* gp1  = cf2 + n_cf;
    float* gp2  = gp1 + n_gp;

    dim3 g1(H_, B_);        // 1024 blocks: 1 row, 4 waves x 16 ch
    dim3 g2(H_, B_, 2);     // 2048 blocks: 1 row, 4 waves x 8 ch

    prep_kernel<<<g1, 256, 0, stream>>>(x, sw1, sb1, sstd1, s1, gp1);
    cfk<<<1, 256, 0, stream>>>(gp1, cw1_1, cb1_1, cw2_1, cb2_1, cstd1, cf1);
    apply_kernel<true><<<g1, 256, 0, stream>>>(x, s1, cf1, sw2, sb2, sstd2,
                                               nullptr, out1, s2, gp2);
    cfk<<<1, 256, 0, stream>>>(gp2, cw1_2, cb1_2, cw2_2, cb2_2, cstd2, cf2);
    apply_kernel<false><<<g2, 256, 0, stream>>>(out1, s2, cf2, nullptr, nullptr,
                                                nullptr, x, outp, nullptr, nullptr);
}

// Round 11
// 184.766 us; speedup vs baseline: 2.1238x; 1.0023x over previous
//
#include <hip/hip_runtime.h>

#define B_ 4
#define C_ 64
#define H_ 256
#define W_ 256
#define HW_ (H_*W_)
#define MID_ 12
#define NPB_ 256   // gap partial slots per image (= one per row)

typedef float f32x4 __attribute__((ext_vector_type(4)));

#define WAITV0() do { \
        asm volatile("s_waitcnt vmcnt(0)" ::: "memory"); \
        __builtin_amdgcn_sched_barrier(0); \
    } while (0)

__device__ __forceinline__ float wave_reduce64(float v) {
#pragma unroll
    for (int off = 32; off; off >>= 1) v += __shfl_xor(v, off, 64);
    return v;
}

// FilterNorm over 9 taps, vectorized over 4 px; writes to sp (stride HW_)
__device__ __forceinline__ void fnorm4_store(const float4* t9,
    const float* __restrict__ sstd, float* sp) {
    float4 mean = make_float4(0, 0, 0, 0);
#pragma unroll
    for (int t = 0; t < 9; ++t) {
        mean.x += t9[t].x; mean.y += t9[t].y; mean.z += t9[t].z; mean.w += t9[t].w;
    }
    mean.x *= (1.f/9.f); mean.y *= (1.f/9.f); mean.z *= (1.f/9.f); mean.w *= (1.f/9.f);
    float4 var = make_float4(0, 0, 0, 0);
#pragma unroll
    for (int t = 0; t < 9; ++t) {
        float dx = t9[t].x - mean.x, dy = t9[t].y - mean.y;
        float dz = t9[t].z - mean.z, dw = t9[t].w - mean.w;
        var.x = fmaf(dx, dx, var.x); var.y = fmaf(dy, dy, var.y);
        var.z = fmaf(dz, dz, var.z); var.w = fmaf(dw, dw, var.w);
    }
    float ix = 1.f / (sqrtf(var.x * (1.f/8.f)) + 1e-10f);
    float iy = 1.f / (sqrtf(var.y * (1.f/8.f)) + 1e-10f);
    float iz = 1.f / (sqrtf(var.z * (1.f/8.f)) + 1e-10f);
    float iw = 1.f / (sqrtf(var.w * (1.f/8.f)) + 1e-10f);
#pragma unroll
    for (int t = 0; t < 9; ++t) {
        float sd = sstd[t];
        *(float4*)(sp + (size_t)t * HW_) = make_float4(
            (t9[t].x - mean.x) * ix * sd, (t9[t].y - mean.y) * iy * sd,
            (t9[t].z - mean.z) * iz * sd, (t9[t].w - mean.w) * iw * sd);
    }
}

// ---------------- prep: read x once -> s1 + gap1 partials ----------------
// block = 1 row, 4 waves x 16 channels; lane = 4 px (float4). grid (H, B).
// Channel loads issued via asm batches (4 ch), depth-2 pipeline.
__global__ __launch_bounds__(256) void prep_kernel(const float* __restrict__ x,
    const float* __restrict__ sw, const float* __restrict__ sb,
    const float* __restrict__ sstd, float* __restrict__ sarr, float* __restrict__ gp) {
    const int lane = threadIdx.x & 63, wv = threadIdx.x >> 6;
    const int row = blockIdx.x;
    const int b = blockIdx.y;
    const int c0 = wv * 16;
    const int pix = row * W_ + lane * 4;
    __shared__ float4 stl[3][9][64];

    float4 st[9];
#pragma unroll
    for (int t = 0; t < 9; ++t) st[t] = make_float4(0, 0, 0, 0);

    const float* xb0 = x + (size_t)b * C_ * HW_;   // wave-uniform base
    f32x4 vA[4], vB[4];

#define P_ISSUE(BUF, CC) do {                                                 \
        _Pragma("unroll")                                                     \
        for (int i_ = 0; i_ < 4; ++i_) {                                      \
            int vo_ = (pix + ((CC) + i_) * HW_) * 4;                          \
            asm volatile("global_load_dwordx4 %0, %1, %2"                     \
                         : "=v"(BUF[i_]) : "v"(vo_), "s"(xb0));               \
        }                                                                     \
    } while (0)

#define P_COMP(BUF, CC) do {                                                  \
        _Pragma("unroll")                                                     \
        for (int i_ = 0; i_ < 4; ++i_) {                                      \
            const int c_ = (CC) + i_;                                         \
            f32x4 v_ = BUF[i_];                                               \
            _Pragma("unroll")                                                 \
            for (int t_ = 0; t_ < 9; ++t_) {                                  \
                const float wt_ = sw[t_ * C_ + c_];                           \
                st[t_].x = fmaf(v_[0], wt_, st[t_].x);                        \
                st[t_].y = fmaf(v_[1], wt_, st[t_].y);                        \
                st[t_].z = fmaf(v_[2], wt_, st[t_].z);                        \
                st[t_].w = fmaf(v_[3], wt_, st[t_].w);                        \
            }                                                                 \
            float g_ = wave_reduce64(((v_[0] + v_[1]) + (v_[2] + v_[3])));    \
            if (lane == 0) gp[((size_t)b * C_ + c_) * NPB_ + blockIdx.x] = g_; \
        }                                                                     \
    } while (0)

    P_ISSUE(vA, c0);
    WAITV0();
#pragma unroll
    for (int k = 0; k < 16; k += 8) {
        P_ISSUE(vB, c0 + k + 4);
        P_COMP(vA, c0 + k);
        WAITV0();
        if (k + 8 < 16) P_ISSUE(vA, c0 + k + 8);
        P_COMP(vB, c0 + k + 4);
        WAITV0();
    }
#undef P_ISSUE
#undef P_COMP

    if (wv) {
#pragma unroll
        for (int t = 0; t < 9; ++t) stl[wv - 1][t][lane] = st[t];
    }
    __syncthreads();
    if (wv == 0) {
#pragma unroll
        for (int t = 0; t < 9; ++t) {
            float bb = sb[t];
#pragma unroll
            for (int j = 0; j < 3; ++j) {
                float4 o = stl[j][t][lane];
                st[t].x += o.x; st[t].y += o.y; st[t].z += o.z; st[t].w += o.w;
            }
            st[t].x += bb; st[t].y += bb; st[t].z += bb; st[t].w += bb;
        }
        fnorm4_store(st, sstd, sarr + ((size_t)b * 9) * HW_ + pix);
    }
}

// ------ cfk: reduce gap partials + SE MLP + FilterNorm -> cf (B,C,12 padded) ------
__global__ __launch_bounds__(256) void cfk(const float* __restrict__ gp,
    const float* __restrict__ cw1, const float* __restrict__ cb1,
    const float* __restrict__ cw2, const float* __restrict__ cb2,
    const float* __restrict__ cstd, float* __restrict__ cf) {
    const int tid = threadIdx.x;
    const int b = tid >> 6, c = tid & 63;
    __shared__ float gsm[B_][C_];
    __shared__ float hsm[B_][MID_];
    {
        const float4* p4 = (const float4*)(gp + ((size_t)b * C_ + c) * NPB_);
        float s = 0.f;
#pragma unroll 8
        for (int i = 0; i < NPB_ / 4; ++i) { float4 v = p4[i]; s += (v.x + v.y) + (v.z + v.w); }
        gsm[b][c] = s * (1.f / HW_);
    }
    __syncthreads();
    if (tid < B_ * MID_) {
        int b2 = tid / MID_, m = tid % MID_;
        float a = cb1[m];
        for (int cc = 0; cc < C_; ++cc) a = fmaf(gsm[b2][cc], cw1[m * C_ + cc], a);
        hsm[b2][m] = fmaxf(a, 0.f);
    }
    __syncthreads();
    float v[9];
    float mean = 0.f;
#pragma unroll
    for (int t = 0; t < 9; ++t) {
        int o = c * 9 + t;
        float a = cb2[o];
#pragma unroll
        for (int m = 0; m < MID_; ++m) a = fmaf(hsm[b][m], cw2[o * MID_ + m], a);
        v[t] = a;
        mean += a;
    }
    mean *= (1.f / 9.f);
    float var = 0.f;
#pragma unroll
    for (int t = 0; t < 9; ++t) { float d = v[t] - mean; var += d * d; }
    float inv = 1.f / (sqrtf(var * (1.f / 8.f)) + 1e-10f);
    float* o12 = cf + ((size_t)b * C_ + c) * 12;
#pragma unroll
    for (int t = 0; t < 9; ++t) o12[t] = (v[t] - mean) * inv * cstd[c * 9 + t];
    o12[9] = 0.f; o12[10] = 0.f; o12[11] = 0.f;
}

// ---------- apply: full-row block, channels split across waves ----------
// asm-issued load batches (4 ch x 3 rows [+resid]), depth-2, vmcnt(0) drains.
// PASS1: grid (H, B), 16 ch/wave, fused relu + s_next + gap.
// PASS2: grid (H, B, 2), 8 ch/wave, + residual.
template<bool PASS1>
__global__ __launch_bounds__(256) void apply_kernel(const float* __restrict__ in,
    const float* __restrict__ sarr, const float* __restrict__ cf,
    const float* __restrict__ swn, const float* __restrict__ sbn,
    const float* __restrict__ sstdn, const float* __restrict__ resid,
    float* __restrict__ out, float* __restrict__ snext, float* __restrict__ gpn) {
    const int lane = threadIdx.x & 63, wv = threadIdx.x >> 6;
    const int row = blockIdx.x;
    const int b = blockIdx.y;
    constexpr int NCHW = PASS1 ? 16 : 8;
    const int c0 = PASS1 ? (wv * 16) : (blockIdx.z * 32 + wv * 8);
    const int pix = row * W_ + lane * 4;

    const bool rup = row > 0, rdn = row < H_ - 1;
    const int offUp = rup ? -W_ : 0;
    const int offDn = rdn ? W_ : 0;
    const float fup = rup ? 1.f : 0.f;
    const float fdn = rdn ? 1.f : 0.f;

    // per-pixel s taps; fold ALL edge masks here
    float4 s0t[9];
    {
        const float* sp = sarr + ((size_t)b * 9) * HW_ + pix;
#pragma unroll
        for (int t = 0; t < 9; ++t) s0t[t] = *(const float4*)(sp + (size_t)t * HW_);
#pragma unroll
        for (int t = 0; t < 3; ++t) {
            s0t[t].x *= fup; s0t[t].y *= fup; s0t[t].z *= fup; s0t[t].w *= fup;
            s0t[t + 6].x *= fdn; s0t[t + 6].y *= fdn; s0t[t + 6].z *= fdn; s0t[t + 6].w *= fdn;
        }
        if (lane == 0)  { s0t[0].x = 0.f; s0t[3].x = 0.f; s0t[6].x = 0.f; }
        if (lane == 63) { s0t[2].w = 0.f; s0t[5].w = 0.f; s0t[8].w = 0.f; }
    }

    float4 nt[9];
    if (PASS1) {
#pragma unroll
        for (int t = 0; t < 9; ++t) nt[t] = make_float4(0, 0, 0, 0);
    }

    const float* inb0 = in + (size_t)b * C_ * HW_;      // wave-uniform base
    const float* rb0  = PASS1 ? in : (resid + (size_t)b * C_ * HW_);
    const float* cfb  = cf + ((size_t)b * C_) * 12;
    float* outp = out + (size_t)b * C_ * HW_ + pix;

    f32x4 A[4][3], Bv[4][3], rA[4], rB[4];

#define ISSUE(BUF, RBUF, CH0) do {                                            \
        _Pragma("unroll")                                                     \
        for (int i_ = 0; i_ < 4; ++i_) {                                      \
            int voM_ = (pix + ((CH0) + i_) * HW_) * 4;                        \
            int voU_ = voM_ + offUp * 4;                                      \
            int voD_ = voM_ + offDn * 4;                                      \
            asm volatile("global_load_dwordx4 %0, %1, %2"                     \
                         : "=v"(BUF[i_][0]) : "v"(voU_), "s"(inb0));          \
            asm volatile("global_load_dwordx4 %0, %1, %2"                     \
                         : "=v"(BUF[i_][1]) : "v"(voM_), "s"(inb0));          \
            asm volatile("global_load_dwordx4 %0, %1, %2"                     \
                         : "=v"(BUF[i_][2]) : "v"(voD_), "s"(inb0));          \
            if (!PASS1)                                                       \
                asm volatile("global_load_dwordx4 %0, %1, %2"                 \
                             : "=v"(RBUF[i_]) : "v"(voM_), "s"(rb0));         \
        }                                                                     \
    } while (0)

#define COMPB(BUF, RBUF, CH0) do {                                            \
        _Pragma("unroll")                                                     \
        for (int i_ = 0; i_ < 4; ++i_) {                                      \
            const int ch_ = (CH0) + i_;                                       \
            const float* cfc_ = cfb + (size_t)ch_ * 12;                       \
            float4 acc_ = make_float4(0.f, 0.f, 0.f, 0.f);                    \
            _Pragma("unroll")                                                 \
            for (int dr_ = 0; dr_ < 3; ++dr_) {                               \
                f32x4 v_ = BUF[i_][dr_];                                      \
                float w0_ = __shfl_up(v_[3], 1, 64);                          \
                float w5_ = __shfl_down(v_[0], 1, 64);                        \
                const float w_[6] = {w0_, v_[0], v_[1], v_[2], v_[3], w5_};   \
                _Pragma("unroll")                                             \
                for (int dc_ = 0; dc_ < 3; ++dc_) {                           \
                    const int t_ = dr_ * 3 + dc_;                             \
                    const float cft_ = cfc_[t_];                              \
                    acc_.x = fmaf(w_[dc_ + 0] * s0t[t_].x, cft_, acc_.x);     \
                    acc_.y = fmaf(w_[dc_ + 1] * s0t[t_].y, cft_, acc_.y);     \
                    acc_.z = fmaf(w_[dc_ + 2] * s0t[t_].z, cft_, acc_.z);     \
                    acc_.w = fmaf(w_[dc_ + 3] * s0t[t_].w, cft_, acc_.w);     \
                }                                                             \
            }                                                                 \
            float4 o_;                                                        \
            if (PASS1) {                                                      \
                o_.x = fmaxf(acc_.x, 0.f); o_.y = fmaxf(acc_.y, 0.f);         \
                o_.z = fmaxf(acc_.z, 0.f); o_.w = fmaxf(acc_.w, 0.f);         \
                _Pragma("unroll")                                             \
                for (int t_ = 0; t_ < 9; ++t_) {                              \
                    const float wt_ = swn[t_ * C_ + ch_];                     \
                    nt[t_].x = fmaf(o_.x, wt_, nt[t_].x);                     \
                    nt[t_].y = fmaf(o_.y, wt_, nt[t_].y);                     \
                    nt[t_].z = fmaf(o_.z, wt_, nt[t_].z);                     \
                    nt[t_].w = fmaf(o_.w, wt_, nt[t_].w);                     \
                }                                                             \
                float g_ = wave_reduce64(((o_.x + o_.y) + (o_.z + o_.w)));    \
                if (lane == 0) gpn[((size_t)b * C_ + ch_) * NPB_ + blockIdx.x] = g_; \
            } else {                                                          \
                o_.x = acc_.x + RBUF[i_][0]; o_.y = acc_.y + RBUF[i_][1];     \
                o_.z = acc_.z + RBUF[i_][2]; o_.w = acc_.w + RBUF[i_][3];     \
            }                                                                 \
            *(float4*)(outp + (size_t)ch_ * HW_) = o_;                        \
        }                                                                     \
    } while (0)

    ISSUE(A, rA, c0);
    WAITV0();
#pragma unroll
    for (int k = 0; k < NCHW; k += 8) {
        ISSUE(Bv, rB, c0 + k + 4);
        COMPB(A, rA, c0 + k);
        WAITV0();
        if (k + 8 < NCHW) ISSUE(A, rA, c0 + k + 8);
        COMPB(Bv, rB, c0 + k + 4);
        WAITV0();
    }
#undef ISSUE
#undef COMPB

    if constexpr (PASS1) {
        __shared__ float4 ntl[3][9][64];
        if (wv) {
#pragma unroll
            for (int t = 0; t < 9; ++t) ntl[wv - 1][t][lane] = nt[t];
        }
        __syncthreads();
        if (wv == 0) {
#pragma unroll
            for (int t = 0; t < 9; ++t) {
                float bb = sbn[t];
#pragma unroll
                for (int j = 0; j < 3; ++j) {
                    float4 o = ntl[j][t][lane];
                    nt[t].x += o.x; nt[t].y += o.y; nt[t].z += o.z; nt[t].w += o.w;
                }
                nt[t].x += bb; nt[t].y += bb; nt[t].z += bb; nt[t].w += bb;
            }
            fnorm4_store(nt, sstdn, snext + ((size_t)b * 9) * HW_ + pix);
        }
    }
}

extern "C" void kernel_launch(void* const* d_in, const int* in_sizes, int n_in,
                              void* d_out, int out_size, void* d_ws, size_t ws_size,
                              hipStream_t stream) {
    const float* x     = (const float*)d_in[0];
    const float* sw1   = (const float*)d_in[1];
    const float* sb1   = (const float*)d_in[2];
    const float* sstd1 = (const float*)d_in[3];
    const float* cw1_1 = (const float*)d_in[4];
    const float* cb1_1 = (const float*)d_in[5];
    const float* cw2_1 = (const float*)d_in[6];
    const float* cb2_1 = (const float*)d_in[7];
    const float* cstd1 = (const float*)d_in[8];
    const float* sw2   = (const float*)d_in[9];
    const float* sb2   = (const float*)d_in[10];
    const float* sstd2 = (const float*)d_in[11];
    const float* cw1_2 = (const float*)d_in[12];
    const float* cb1_2 = (const float*)d_in[13];
    const float* cw2_2 = (const float*)d_in[14];
    const float* cb2_2 = (const float*)d_in[15];
    const float* cstd2 = (const float*)d_in[16];
    float* outp = (float*)d_out;

    const size_t n_out1 = (size_t)B_ * C_ * HW_;     // 16,777,216
    const size_t n_s    = (size_t)B_ * 9 * HW_;      // 2,359,296
    const size_t n_cf   = (size_t)B_ * C_ * 12;      // 3,072 (padded)
    const size_t n_gp   = (size_t)B_ * C_ * NPB_;    // 65,536
    const size_t need = (n_out1 + 2 * n_s + 2 * n_cf + 2 * n_gp) * sizeof(float);
    if (ws_size < need) return;

    float* out1 = (float*)d_ws;
    float* s1   = out1 + n_out1;
    float* s2   = s1 + n_s;
    float* cf1  = s2 + n_s;
    float* cf2  = cf1 + n_cf;
    float* gp1  = cf2 + n_cf;
    float* gp2  = gp1 + n_gp;

    dim3 g1(H_, B_);        // 1024 blocks: 1 row, 4 waves x 16 ch
    dim3 g2(H_, B_, 2);     // 2048 blocks: 1 row, 4 waves x 8 ch

    prep_kernel<<<g1, 256, 0, stream>>>(x, sw1, sb1, sstd1, s1, gp1);
    cfk<<<1, 256, 0, stream>>>(gp1, cw1_1, cb1_1, cw2_1, cb2_1, cstd1, cf1);
    apply_kernel<true><<<g1, 256, 0, stream>>>(x, s1, cf1, sw2, sb2, sstd2,
                                               nullptr, out1, s2, gp2);
    cfk<<<1, 256, 0, stream>>>(gp2, cw1_2, cb1_2, cw2_2, cb2_2, cstd2, cf2);
    apply_kernel<false><<<g2, 256, 0, stream>>>(out1, s2, cf2, nullptr, nullptr,
                                                nullptr, x, outp, nullptr, nullptr);
}

// Round 12
// 154.936 us; speedup vs baseline: 2.5327x; 1.1925x over previous
//
#include <hip/hip_runtime.h>

#define B_ 4
#define C_ 64
#define H_ 256
#define W_ 256
#define HW_ (H_*W_)
#define MID_ 12
#define NPB_ 256   // gap partial slots per image (= one per row)

__device__ __forceinline__ float wave_reduce64(float v) {
#pragma unroll
    for (int off = 32; off; off >>= 1) v += __shfl_xor(v, off, 64);
    return v;
}

// FilterNorm over 9 taps, vectorized over 4 px; writes to sp (stride HW_)
__device__ __forceinline__ void fnorm4_store(const float4* t9,
    const float* __restrict__ sstd, float* sp) {
    float4 mean = make_float4(0, 0, 0, 0);
#pragma unroll
    for (int t = 0; t < 9; ++t) {
        mean.x += t9[t].x; mean.y += t9[t].y; mean.z += t9[t].z; mean.w += t9[t].w;
    }
    mean.x *= (1.f/9.f); mean.y *= (1.f/9.f); mean.z *= (1.f/9.f); mean.w *= (1.f/9.f);
    float4 var = make_float4(0, 0, 0, 0);
#pragma unroll
    for (int t = 0; t < 9; ++t) {
        float dx = t9[t].x - mean.x, dy = t9[t].y - mean.y;
        float dz = t9[t].z - mean.z, dw = t9[t].w - mean.w;
        var.x = fmaf(dx, dx, var.x); var.y = fmaf(dy, dy, var.y);
        var.z = fmaf(dz, dz, var.z); var.w = fmaf(dw, dw, var.w);
    }
    float ix = 1.f / (sqrtf(var.x * (1.f/8.f)) + 1e-10f);
    float iy = 1.f / (sqrtf(var.y * (1.f/8.f)) + 1e-10f);
    float iz = 1.f / (sqrtf(var.z * (1.f/8.f)) + 1e-10f);
    float iw = 1.f / (sqrtf(var.w * (1.f/8.f)) + 1e-10f);
#pragma unroll
    for (int t = 0; t < 9; ++t) {
        float sd = sstd[t];
        *(float4*)(sp + (size_t)t * HW_) = make_float4(
            (t9[t].x - mean.x) * ix * sd, (t9[t].y - mean.y) * iy * sd,
            (t9[t].z - mean.z) * iz * sd, (t9[t].w - mean.w) * iw * sd);
    }
}

// ---------------- prep: read in once -> s (normalized) + gap partials ----------------
// block = 1 row, 4 waves x 16 channels; lane = 4 px (float4). grid (H, B).
__global__ __launch_bounds__(256) void prep_kernel(const float* __restrict__ x,
    const float* __restrict__ sw, const float* __restrict__ sb,
    const float* __restrict__ sstd, float* __restrict__ sarr, float* __restrict__ gp) {
    const int lane = threadIdx.x & 63, wv = threadIdx.x >> 6;
    const int row = blockIdx.x;
    const int b = blockIdx.y;
    const int c0 = wv * 16;
    const int pix = row * W_ + lane * 4;
    __shared__ float4 stl[3][9][64];

    float4 st[9];
#pragma unroll
    for (int t = 0; t < 9; ++t) st[t] = make_float4(0, 0, 0, 0);

    const float* xb = x + (size_t)b * C_ * HW_ + pix;
    float4 vA[4], vB[4];
#pragma unroll
    for (int i = 0; i < 4; ++i) vA[i] = *(const float4*)(xb + (size_t)(c0 + i) * HW_);

#define PREP_COMP(BUF, CC) do {                                               \
        _Pragma("unroll")                                                     \
        for (int i_ = 0; i_ < 4; ++i_) {                                      \
            const int c_ = (CC) + i_;                                         \
            float4 v_ = BUF[i_];                                              \
            _Pragma("unroll")                                                 \
            for (int t_ = 0; t_ < 9; ++t_) {                                  \
                const float wt_ = sw[t_ * C_ + c_];                           \
                st[t_].x = fmaf(v_.x, wt_, st[t_].x);                         \
                st[t_].y = fmaf(v_.y, wt_, st[t_].y);                         \
                st[t_].z = fmaf(v_.z, wt_, st[t_].z);                         \
                st[t_].w = fmaf(v_.w, wt_, st[t_].w);                         \
            }                                                                 \
            float g_ = wave_reduce64(((v_.x + v_.y) + (v_.z + v_.w)));        \
            if (lane == 0) gp[((size_t)b * C_ + c_) * NPB_ + blockIdx.x] = g_; \
        }                                                                     \
    } while (0)

    for (int k = 0; k < 16; k += 8) {
#pragma unroll
        for (int i = 0; i < 4; ++i) vB[i] = *(const float4*)(xb + (size_t)(c0 + k + 4 + i) * HW_);
        PREP_COMP(vA, c0 + k);
        if (k + 8 < 16) {
#pragma unroll
            for (int i = 0; i < 4; ++i) vA[i] = *(const float4*)(xb + (size_t)(c0 + k + 8 + i) * HW_);
        }
        PREP_COMP(vB, c0 + k + 4);
    }
#undef PREP_COMP

    if (wv) {
#pragma unroll
        for (int t = 0; t < 9; ++t) stl[wv - 1][t][lane] = st[t];
    }
    __syncthreads();
    if (wv == 0) {
#pragma unroll
        for (int t = 0; t < 9; ++t) {
            float bb = sb[t];
#pragma unroll
            for (int j = 0; j < 3; ++j) {
                float4 o = stl[j][t][lane];
                st[t].x += o.x; st[t].y += o.y; st[t].z += o.z; st[t].w += o.w;
            }
            st[t].x += bb; st[t].y += bb; st[t].z += bb; st[t].w += bb;
        }
        fnorm4_store(st, sstd, sarr + ((size_t)b * 9) * HW_ + pix);
    }
}

// ------ cfk: reduce gap partials + SE MLP + FilterNorm -> cf (B,C,12 padded) ------
__global__ __launch_bounds__(256) void cfk(const float* __restrict__ gp,
    const float* __restrict__ cw1, const float* __restrict__ cb1,
    const float* __restrict__ cw2, const float* __restrict__ cb2,
    const float* __restrict__ cstd, float* __restrict__ cf) {
    const int tid = threadIdx.x;
    const int b = tid >> 6, c = tid & 63;
    __shared__ float gsm[B_][C_];
    __shared__ float hsm[B_][MID_];
    {
        const float4* p4 = (const float4*)(gp + ((size_t)b * C_ + c) * NPB_);
        float s = 0.f;
#pragma unroll 8
        for (int i = 0; i < NPB_ / 4; ++i) { float4 v = p4[i]; s += (v.x + v.y) + (v.z + v.w); }
        gsm[b][c] = s * (1.f / HW_);
    }
    __syncthreads();
    if (tid < B_ * MID_) {
        int b2 = tid / MID_, m = tid % MID_;
        float a = cb1[m];
        for (int cc = 0; cc < C_; ++cc) a = fmaf(gsm[b2][cc], cw1[m * C_ + cc], a);
        hsm[b2][m] = fmaxf(a, 0.f);
    }
    __syncthreads();
    float v[9];
    float mean = 0.f;
#pragma unroll
    for (int t = 0; t < 9; ++t) {
        int o = c * 9 + t;
        float a = cb2[o];
#pragma unroll
        for (int m = 0; m < MID_; ++m) a = fmaf(hsm[b][m], cw2[o * MID_ + m], a);
        v[t] = a;
        mean += a;
    }
    mean *= (1.f / 9.f);
    float var = 0.f;
#pragma unroll
    for (int t = 0; t < 9; ++t) { float d = v[t] - mean; var += d * d; }
    float inv = 1.f / (sqrtf(var * (1.f / 8.f)) + 1e-10f);
    float* o12 = cf + ((size_t)b * C_ + c) * 12;
#pragma unroll
    for (int t = 0; t < 9; ++t) o12[t] = (v[t] - mean) * inv * cstd[c * 9 + t];
    o12[9] = 0.f; o12[10] = 0.f; o12[11] = 0.f;
}

// ---------- apply: pure channel-parallel 3x3 dynamic filter ----------
// block = 64x4 px tile, 8 channels; 1 px/thread; grid (W/64, H/4, B*8) = 8192.
// Edge handling folded into s0/off9; inner loop branchless, TLP-driven.
template<bool RELU, bool RESID>
__global__ __launch_bounds__(256) void apply_kernel(const float* __restrict__ in,
    const float* __restrict__ sarr, const float* __restrict__ cf,
    const float* __restrict__ resid, float* __restrict__ out) {
    const int lane = threadIdx.x & 63, wv = threadIdx.x >> 6;
    const int col = blockIdx.x * 64 + lane;
    const int row = blockIdx.y * 4 + wv;
    const int z = blockIdx.z;
    const int b = z >> 3;
    const int c0 = (z & 7) * 8;
    const int pix = row * W_ + col;

    // s taps at my pixel; fold ALL edge masking here
    float s0[9];
    int off9[9];
    {
        const float* sp = sarr + ((size_t)b * 9) * HW_ + pix;
#pragma unroll
        for (int t = 0; t < 9; ++t) s0[t] = sp[(size_t)t * HW_];
#pragma unroll
        for (int dr = -1; dr <= 1; ++dr)
#pragma unroll
            for (int dc = -1; dc <= 1; ++dc) {
                const int t = (dr + 1) * 3 + (dc + 1);
                const bool ok = (row + dr >= 0) && (row + dr < H_) &&
                                (col + dc >= 0) && (col + dc < W_);
                off9[t] = ok ? (pix + dr * W_ + dc) : pix;
                if (!ok) s0[t] = 0.f;
            }
    }

    const float* inb = in + ((size_t)b * C_ + c0) * HW_;
    const float* cfb = cf + ((size_t)b * C_ + c0) * 12;
    const float* rb  = RESID ? (resid + ((size_t)b * C_ + c0) * HW_ + pix) : nullptr;
    float* outp = out + ((size_t)b * C_ + c0) * HW_ + pix;

#pragma unroll
    for (int c = 0; c < 8; ++c) {
        const float* p = inb + (size_t)c * HW_;
        float m[9];
#pragma unroll
        for (int t = 0; t < 9; ++t) m[t] = p[off9[t]];
        const float* cfc = cfb + (size_t)c * 12;
        float acc = 0.f;
#pragma unroll
        for (int t = 0; t < 9; ++t) acc = fmaf(m[t] * s0[t], cfc[t], acc);
        float o = RELU ? fmaxf(acc, 0.f) : acc;
        if (RESID) o += rb[(size_t)c * HW_];
        outp[(size_t)c * HW_] = o;
    }
}

extern "C" void kernel_launch(void* const* d_in, const int* in_sizes, int n_in,
                              void* d_out, int out_size, void* d_ws, size_t ws_size,
                              hipStream_t stream) {
    const float* x     = (const float*)d_in[0];
    const float* sw1   = (const float*)d_in[1];
    const float* sb1   = (const float*)d_in[2];
    const float* sstd1 = (const float*)d_in[3];
    const float* cw1_1 = (const float*)d_in[4];
    const float* cb1_1 = (const float*)d_in[5];
    const float* cw2_1 = (const float*)d_in[6];
    const float* cb2_1 = (const float*)d_in[7];
    const float* cstd1 = (const float*)d_in[8];
    const float* sw2   = (const float*)d_in[9];
    const float* sb2   = (const float*)d_in[10];
    const float* sstd2 = (const float*)d_in[11];
    const float* cw1_2 = (const float*)d_in[12];
    const float* cb1_2 = (const float*)d_in[13];
    const float* cw2_2 = (const float*)d_in[14];
    const float* cb2_2 = (const float*)d_in[15];
    const float* cstd2 = (const float*)d_in[16];
    float* outp = (float*)d_out;

    const size_t n_out1 = (size_t)B_ * C_ * HW_;     // 16,777,216
    const size_t n_s    = (size_t)B_ * 9 * HW_;      // 2,359,296
    const size_t n_cf   = (size_t)B_ * C_ * 12;      // 3,072 (padded)
    const size_t n_gp   = (size_t)B_ * C_ * NPB_;    // 65,536
    const size_t need = (n_out1 + 2 * n_s + 2 * n_cf + 2 * n_gp) * sizeof(float);
    if (ws_size < need) return;

    float* out1 = (float*)d_ws;
    float* s1   = out1 + n_out1;
    float* s2   = s1 + n_s;
    float* cf1  = s2 + n_s;
    float* cf2  = cf1 + n_cf;
    float* gp1  = cf2 + n_cf;
    float* gp2  = gp1 + n_gp;

    dim3 gprep(H_, B_);              // 1024 blocks
    dim3 gapply(W_ / 64, H_ / 4, B_ * 8);   // 8192 blocks, 8 ch each

    // pass 1
    prep_kernel<<<gprep, 256, 0, stream>>>(x, sw1, sb1, sstd1, s1, gp1);
    cfk<<<1, 256, 0, stream>>>(gp1, cw1_1, cb1_1, cw2_1, cb2_1, cstd1, cf1);
    apply_kernel<true, false><<<gapply, 256, 0, stream>>>(x, s1, cf1, nullptr, out1);
    // pass 2 (s2/gap2 from relu'd out1 via prep2 = prep)
    prep_kernel<<<gprep, 256, 0, stream>>>(out1, sw2, sb2, sstd2, s2, gp2);
    cfk<<<1, 256, 0, stream>>>(gp2, cw1_2, cb1_2, cw2_2, cb2_2, cstd2, cf2);
    apply_kernel<false, true><<<gapply, 256, 0, stream>>>(out1, s2, cf2, x, outp);
}